// Round 24
// baseline (278.468 us; speedup 1.0000x reference)
//
#include <hip/hip_runtime.h>
#include <math.h>

constexpr int Hc = 80, Wc = 80, Bn = 4, C1 = 256, C2 = 256;
constexpr int HWn = Hc * Wc;          // 6400
constexpr int NPIX = Bn * HWn;        // 25600
constexpr int OFFC = 27;
constexpr int KK   = 2304;            // C1*9

typedef short bf16x8 __attribute__((ext_vector_type(8)));
typedef float f32x4  __attribute__((ext_vector_type(4)));

__device__ __forceinline__ unsigned f2bf(float f) {   // RNE to bf16 bits
    unsigned u = __float_as_uint(f);
    return (u + 0x7FFF + ((u >> 16) & 1)) >> 16;
}

// pack 2 floats -> 1 u32 of 2 bf16 via cvt_pk (RNE)
__device__ __forceinline__ unsigned packhi2(float v0, float v1) {
    unsigned h;
    asm("v_cvt_pk_bf16_f32 %0, %1, %2" : "=v"(h) : "v"(v0), "v"(v1));
    return h;
}

// ---------------- kernel 0a: weight prep -> per-step B images, K-MAJOR ----------
// wB1[s][kg][oc][8] bf16, s = p*8+cc (72 steps), kg = k-quad (8 k each).
__global__ __launch_bounds__(256) void k_wprep(const float* __restrict__ weight,
                                               unsigned short* __restrict__ wB1)
{
    int e = blockIdx.x * 256 + threadIdx.x;   // 0 .. 589823
    int kin = e & 7;
    int oc  = (e >> 3) & 255;
    int kg  = (e >> 11) & 3;
    int s   = e >> 13;                        // 0..71
    int p   = s >> 3, cc = s & 7;
    float w = weight[((size_t)oc * C1 + cc * 32 + kg * 8 + kin) * 9 + p];
    wB1[e] = (unsigned short)f2bf(w);
}

// ---------------- kernel 0b: offset-conv MFMA weight prep -> wOB[s][32][32] ----
__global__ __launch_bounds__(256) void k_wobprep(const float* __restrict__ w_off,
                                                 unsigned short* __restrict__ wOB)
{
    int e = blockIdx.x * 256 + threadIdx.x;   // 0 .. 73727
    int k  = e & 31;
    int oc = (e >> 5) & 31;
    int s  = e >> 10;                         // 0..71
    int p  = s >> 3, cc = s & 7;
    float v = 0.f;
    if (oc < 27) v = w_off[((size_t)oc * C1 + cc * 32 + k) * 9 + p];
    wOB[e] = (unsigned short)f2bf(v);
}

// ---------------- kernel 0c: x transpose -> xT[b][hw][c] (f32) + xTb (bf16) ----
__global__ __launch_bounds__(256) void k_xtrans(const float* __restrict__ x,
                                                float* __restrict__ xT,
                                                unsigned short* __restrict__ xTb)
{
    __shared__ float tile[32][33];
    int bid = blockIdx.x;                 // b*(200*8) + hwt*8 + ct
    int ct  = bid & 7;
    int hwt = (bid >> 3) % 200;
    int b   = bid / 1600;
    int c0  = ct * 32, hw0 = hwt * 32;
    int tid = threadIdx.x;
    int col = tid & 31, rw = tid >> 5;    // 8 rows per pass
    const float* xb = x + (size_t)b * C1 * HWn;
    #pragma unroll
    for (int k = 0; k < 4; ++k) {
        int r = rw + k * 8;               // c-index
        tile[r][col] = xb[(size_t)(c0 + r) * HWn + hw0 + col];
    }
    __syncthreads();
    float* xo = xT + ((size_t)b * HWn + hw0) * C1 + c0;
    unsigned short* xob = xTb + ((size_t)b * HWn + hw0) * C1 + c0;
    #pragma unroll
    for (int k = 0; k < 4; ++k) {
        int r = rw + k * 8;               // hw-index
        float v = tile[col][r];
        xo[(size_t)r * C1 + col]  = v;
        xob[(size_t)r * C1 + col] = (unsigned short)f2bf(v);
    }
}

// ---------------- kernel 1b: offset conv v4 — MFMA, no LDS, no barriers --------
__global__ __launch_bounds__(256) void k_offmfma(const unsigned short* __restrict__ xTb,
                                                 const unsigned short* __restrict__ wOB,
                                                 const float* __restrict__ b_off,
                                                 float* __restrict__ off)
{
    int t  = threadIdx.x;
    int wv = t >> 6, lane = t & 63;
    int li = lane & 15, kg = lane >> 4;
    int mi = wv & 1;                   // m-tile (16 px)
    int nj = wv >> 1;                  // n-tile (16 oc)

    int mtile = ((blockIdx.x & 7) * 100) + (blockIdx.x >> 3);
    int m0  = mtile * 32;
    int b   = m0 / HWn;                // uniform per block
    int hw0 = m0 - b * HWn;
    int pxl = hw0 + mi * 16 + li;      // this lane's hw (A row)
    int h = pxl / Wc, w = pxl - h * Wc;

    const unsigned short* xb = xTb + (size_t)b * HWn * C1;

    f32x4 acc = (f32x4){0.f, 0.f, 0.f, 0.f};
    #pragma unroll
    for (int p = 0; p < 9; ++p) {
        int dh = p / 3 - 1, dw = p % 3 - 1;
        int hh = h + dh, ww = w + dw;
        bool valid = (hh >= 0 && hh < Hc && ww >= 0 && ww < Wc);
        int hwp = valid ? (hh * Wc + ww) : 0;
        const unsigned short* arow = xb + (size_t)hwp * C1 + kg * 8;
        const unsigned short* brow = wOB + ((size_t)(p * 8) * 32 + nj * 16 + li) * 32 + kg * 8;
        #pragma unroll
        for (int cc = 0; cc < 8; ++cc) {
            uint4 av = *(const uint4*)(arow + cc * 32);
            if (!valid) av = make_uint4(0, 0, 0, 0);
            uint4 bv = *(const uint4*)(brow + cc * 1024);   // next s: +32*32 u16
            acc = __builtin_amdgcn_mfma_f32_16x16x32_bf16(
                __builtin_bit_cast(bf16x8, av), __builtin_bit_cast(bf16x8, bv), acc, 0, 0, 0);
        }
    }
    int oc = nj * 16 + li;
    if (oc < OFFC) {
        float bs = b_off[oc];
        float4 v;
        v.x = acc[0] + bs; v.y = acc[1] + bs; v.z = acc[2] + bs; v.w = acc[3] + bs;
        int hwd = hw0 + mi * 16 + kg * 4;
        *(float4*)&off[((size_t)b * OFFC + oc) * HWn + hwd] = v;
    }
}

// ---------------- kernel 1c-pre: bilinear metadata table ----------------
__global__ __launch_bounds__(256) void k_meta(const float* __restrict__ off,
                                              int* __restrict__ crdbuf,
                                              float4* __restrict__ w4buf)
{
    int pair = blockIdx.x * 256 + threadIdx.x;   // 0 .. 230399
    int px = pair / 9, p = pair - px * 9;
    int b  = px / HWn, hw = px - b * HWn;
    int h = hw / Wc, w = hw - h * Wc;
    int ii = p / 3, jj = p - ii * 3;

    const float* ob = off + (size_t)b * OFFC * HWn + hw;
    float dy = ob[(2 * p) * HWn];
    float dx = ob[(2 * p + 1) * HWn];
    float mv = ob[(18 + p) * HWn];
    float mask = 1.0f / (1.0f + expf(-mv));
    float ys = dy + (float)(h - 1 + ii);
    float xsv = dx + (float)(w - 1 + jj);
    float y0f = floorf(ys), x0f = floorf(xsv);
    float wy = ys - y0f, wx = xsv - x0f;
    int y0 = (int)y0f, x0 = (int)x0f;
    int y1 = y0 + 1, x1 = x0 + 1;
    float vy0 = (y0 >= 0 && y0 < Hc) ? 1.f : 0.f;
    float vy1 = (y1 >= 0 && y1 < Hc) ? 1.f : 0.f;
    float vx0 = (x0 >= 0 && x0 < Wc) ? 1.f : 0.f;
    float vx1 = (x1 >= 0 && x1 < Wc) ? 1.f : 0.f;
    float4 wv;
    wv.x = mask * (1.f - wy) * (1.f - wx) * vy0 * vx0;
    wv.y = mask * (1.f - wy) * wx         * vy0 * vx1;
    wv.z = mask * wy         * (1.f - wx) * vy1 * vx0;
    wv.w = mask * wy         * wx         * vy1 * vx1;
    int cy0 = min(max(y0, 0), Hc - 1), cy1 = min(max(y1, 0), Hc - 1);
    int cx0 = min(max(x0, 0), Wc - 1), cx1 = min(max(x1, 0), Wc - 1);
    crdbuf[pair] = cy0 | (cy1 << 8) | (cx0 << 16) | (cx1 << 24);
    w4buf[pair]  = wv;
}

// ---------------- kernel 1c: materialize patches v5 (channel-dense reads) -------
__global__ __launch_bounds__(256) void k_gather(const float* __restrict__ xT,
                                                const int* __restrict__ crdbuf,
                                                const float4* __restrict__ w4buf,
                                                unsigned short* __restrict__ Ahi)
{
    int t   = threadIdx.x;
    int wv  = t >> 6, l = t & 63;
    int xcd = blockIdx.x & 7;
    int blk = blockIdx.x >> 3;               // 0..99 within XCD
    int wgl = (xcd * 100 + blk) * 4 + wv;    // global wave 0..3199
    int base = wgl * 72;

    #pragma unroll 2
    for (int i = 0; i < 72; ++i) {
        int pair = base + i;
        int px = pair / 9, p = pair - px * 9;
        int b  = px / HWn;
        int crd = crdbuf[pair];
        float4 w4 = w4buf[pair];
        int cy0 = crd & 255, cy1 = (crd >> 8) & 255;
        int cx0 = (crd >> 16) & 255, cx1 = (crd >> 24) & 255;
        const float* xt = xT + (size_t)b * HWn * C1;
        const float4* g00p = (const float4*)&xt[(size_t)(cy0 * Wc + cx0) * C1];
        const float4* g01p = (const float4*)&xt[(size_t)(cy0 * Wc + cx1) * C1];
        const float4* g10p = (const float4*)&xt[(size_t)(cy1 * Wc + cx0) * C1];
        const float4* g11p = (const float4*)&xt[(size_t)(cy1 * Wc + cx1) * C1];
        float4 g00 = g00p[l], g01 = g01p[l], g10 = g10p[l], g11 = g11p[l];
        float vx = fmaf(w4.x, g00.x, fmaf(w4.y, g01.x, fmaf(w4.z, g10.x, w4.w * g11.x)));
        float vy = fmaf(w4.x, g00.y, fmaf(w4.y, g01.y, fmaf(w4.z, g10.y, w4.w * g11.y)));
        float vz = fmaf(w4.x, g00.z, fmaf(w4.y, g01.z, fmaf(w4.z, g10.z, w4.w * g11.z)));
        float vw = fmaf(w4.x, g00.w, fmaf(w4.y, g01.w, fmaf(w4.z, g10.w, w4.w * g11.w)));
        unsigned h0 = packhi2(vx, vy), h1 = packhi2(vz, vw);
        int s = p * 8 + (l >> 3);
        size_t aidx = ((size_t)s * NPIX + px) * 32 + 4 * (l & 7);
        *(uint2*)&Ahi[aidx] = make_uint2(h0, h1);
    }
}

// ------------- kernel 2: dense streaming MFMA GEMM v13 — 8-wave TLP -------------
// rounds 18-23 falsified barriers/conflicts/LDS/ILP-prefetch (r23: VGPR=64
// proves the compiler collapsed the 4-deep pipeline). Remaining mechanism:
// TLP — occupancy 21% (~1.7 waves/SIMD time-avg) cannot hide latency.
// v13: 512 threads, 8 waves/block, wave = 2 m-frags x 2 nt (32 oc each);
// grid 800 -> 6400 waves = 6.25/SIMD (2x). Per-block traffic unchanged;
// per-wave step = 2 A + 2 B loads + 4 MFMA; latency hidden by wave overlap
// (m114). acc = 16 VGPR/wave.
__global__ __launch_bounds__(512) void k_dmfma(const unsigned short* __restrict__ Ahi,
                                               const unsigned short* __restrict__ wB1,
                                               const float* __restrict__ bias,
                                               float* __restrict__ out)
{
    __shared__ float Tb[32 * 33];      // epilogue transpose only (4224 B)

    int t  = threadIdx.x;
    int wv = t >> 6, lane = t & 63;
    int li = lane & 15, kg = lane >> 4;
    int nh = wv;                       // oc 32-slot (8 waves x 32 oc)

    int mtile = ((blockIdx.x & 7) * 100) + (blockIdx.x >> 3);
    int m0  = mtile * 32;
    int b   = m0 / HWn;
    int hw0 = m0 - b * HWn;
    int row0 = m0 + li;                // m-frag 0 row
    int row1 = m0 + 16 + li;           // m-frag 1 row

    const unsigned short* a0p = Ahi + (size_t)row0 * 32 + kg * 8;
    const unsigned short* a1p = Ahi + (size_t)row1 * 32 + kg * 8;
    const unsigned short* bp  = wB1 + (size_t)(kg * 256 + nh * 32 + li) * 8;

    auto loadA = [&](int s, uint4& h0, uint4& h1) {
        size_t o = (size_t)s * NPIX * 32;
        h0 = *(const uint4*)(a0p + o);
        h1 = *(const uint4*)(a1p + o);
    };
    auto loadB = [&](int s, uint4& b0, uint4& b1) {
        const unsigned short* q = bp + (size_t)s * 8192;
        b0 = *(const uint4*)(q);
        b1 = *(const uint4*)(q + 128);     // nt*16*8 u16
    };

    f32x4 acc[2][2];
    #pragma unroll
    for (int m = 0; m < 2; ++m)
        #pragma unroll
        for (int n = 0; n < 2; ++n) acc[m][n] = (f32x4){0.f, 0.f, 0.f, 0.f};

    uint4 aA0, aA1, bA0, bA1;          // stage A
    uint4 aB0, aB1, bB0, bB1;          // stage B

    auto compute = [&](uint4& c0, uint4& c1, uint4& q0, uint4& q1) {
        bf16x8 a0 = __builtin_bit_cast(bf16x8, c0);
        bf16x8 a1 = __builtin_bit_cast(bf16x8, c1);
        __builtin_amdgcn_s_setprio(1);
        bf16x8 v;
        v = __builtin_bit_cast(bf16x8, q0);
        acc[0][0] = __builtin_amdgcn_mfma_f32_16x16x32_bf16(a0, v, acc[0][0], 0, 0, 0);
        acc[1][0] = __builtin_amdgcn_mfma_f32_16x16x32_bf16(a1, v, acc[1][0], 0, 0, 0);
        v = __builtin_bit_cast(bf16x8, q1);
        acc[0][1] = __builtin_amdgcn_mfma_f32_16x16x32_bf16(a0, v, acc[0][1], 0, 0, 0);
        acc[1][1] = __builtin_amdgcn_mfma_f32_16x16x32_bf16(a1, v, acc[1][1], 0, 0, 0);
        __builtin_amdgcn_s_setprio(0);
    };

    loadA(0, aA0, aA1); loadB(0, bA0, bA1);
    for (int s = 0; s < 72; s += 2) {
        loadA(s + 1, aB0, aB1); loadB(s + 1, bB0, bB1);
        compute(aA0, aA1, bA0, bA1);
        if (s + 2 < 72) { loadA(s + 2, aA0, aA1); loadB(s + 2, bA0, bA1); }
        compute(aB0, aB1, bB0, bB1);
    }

    // ---- epilogue: 8 phases of 32 oc through Tb[32][33] ----
    // D frag: px = m*16 + kg*4 + r ; oc = nh*32 + nt*16 + li.
    // Phase q: oc in [q*32, q*32+32) -> wave nh == q, nt = 0,1.
    #pragma unroll
    for (int q = 0; q < 8; ++q) {
        __syncthreads();
        if (nh == q) {
            #pragma unroll
            for (int nt = 0; nt < 2; ++nt) {
                #pragma unroll
                for (int m = 0; m < 2; ++m) {
                    f32x4 a = acc[m][nt];
                    int rrw = nt * 16 + li;             // oc row 0..31
                    int col = m * 16 + kg * 4;          // pixel col
                    #pragma unroll
                    for (int r = 0; r < 4; ++r)
                        Tb[rrw * 33 + col + r] = a[r];
                }
            }
        }
        __syncthreads();
        int px = t & 31;
        int rw = t >> 5;                    // 0..15
        #pragma unroll
        for (int it = 0; it < 2; ++it) {
            int r  = it * 16 + rw;          // 0..31
            int oc = q * 32 + r;
            out[(size_t)(b * C2 + oc) * HWn + hw0 + px] = Tb[r * 33 + px] + bias[oc];
        }
    }
}

// ---------------- kernel 3: BN stats (per-channel mean, invstd) ----------------
__global__ __launch_bounds__(256) void k_bnstats(const float* __restrict__ out,
                                                 float* __restrict__ stats)
{
    int oc = blockIdx.x;
    double s = 0.0, ss = 0.0;
    for (int i = threadIdx.x; i < NPIX; i += 256) {
        int bb = i / HWn;
        int hw = i - bb * HWn;
        float v = out[(size_t)(bb * C2 + oc) * HWn + hw];
        s  += (double)v;
        ss += (double)v * (double)v;
    }
    __shared__ double ls[256], lss[256];
    ls[threadIdx.x] = s; lss[threadIdx.x] = ss;
    __syncthreads();
    for (int st = 128; st > 0; st >>= 1) {
        if (threadIdx.x < st) {
            ls[threadIdx.x]  += ls[threadIdx.x + st];
            lss[threadIdx.x] += lss[threadIdx.x + st];
        }
        __syncthreads();
    }
    if (threadIdx.x == 0) {
        double mean = ls[0] / (double)NPIX;
        double var  = lss[0] / (double)NPIX - mean * mean;
        stats[oc]       = (float)mean;
        stats[256 + oc] = (float)(1.0 / sqrt(var + 1e-5));
    }
}

// ---------------- kernel 4: BN normalize + affine + SiLU (in-place) ----------------
__global__ __launch_bounds__(256) void k_bnsilu(float* __restrict__ out,
                                                const float* __restrict__ stats,
                                                const float* __restrict__ gamma,
                                                const float* __restrict__ beta)
{
    int n4 = (Bn * C2 * HWn) / 4;
    for (int i = blockIdx.x * blockDim.x + threadIdx.x; i < n4;
         i += gridDim.x * blockDim.x) {
        float4 v = ((float4*)out)[i];
        int e  = i * 4;
        int oc = (e / HWn) & 255;
        float mean = stats[oc];
        float gs   = gamma[oc] * stats[256 + oc];
        float bt   = beta[oc];
        float y;
        y = (v.x - mean) * gs + bt; v.x = y / (1.f + expf(-y));
        y = (v.y - mean) * gs + bt; v.y = y / (1.f + expf(-y));
        y = (v.z - mean) * gs + bt; v.z = y / (1.f + expf(-y));
        y = (v.w - mean) * gs + bt; v.w = y / (1.f + expf(-y));
        ((float4*)out)[i] = v;
    }
}

extern "C" void kernel_launch(void* const* d_in, const int* in_sizes, int n_in,
                              void* d_out, int out_size, void* d_ws, size_t ws_size,
                              hipStream_t stream)
{
    const float* x      = (const float*)d_in[0];
    const float* w_off  = (const float*)d_in[1];
    const float* b_off  = (const float*)d_in[2];
    const float* weight = (const float*)d_in[3];
    const float* bias   = (const float*)d_in[4];
    const float* gamma  = (const float*)d_in[5];
    const float* beta   = (const float*)d_in[6];
    float* out = (float*)d_out;

    // workspace layout (~158 MiB total)
    char* wsb = (char*)d_ws;
    unsigned short* Ahi  = (unsigned short*)(wsb);                 // 117,964,800 B
    float*          xT   = (float*)(wsb + 117964800);              //  26,214,400 B
    unsigned short* xTb  = (unsigned short*)(wsb + 144179200);     //  13,107,200 B
    float*          off  = (float*)(wsb + 157286400);              //   2,764,800 B
    unsigned short* wB1  = (unsigned short*)(wsb + 160051200);     //   1,179,648 B
    unsigned short* wOB  = (unsigned short*)(wsb + 161230848);     //     147,456 B
    int*            crdb = (int*)(wsb + 161378304);                //     921,600 B
    float4*         w4b  = (float4*)(wsb + 162299904);             //   3,686,400 B
    float*         stats = (float*)(wsb + 165986304);              //       2,048 B

    k_wprep    <<<2304, 256, 0, stream>>>(weight, wB1);
    k_wobprep  <<<288, 256, 0, stream>>>(w_off, wOB);
    k_xtrans   <<<6400, 256, 0, stream>>>(x, xT, xTb);
    k_offmfma  <<<800, 256, 0, stream>>>(xTb, wOB, b_off, off);
    k_meta     <<<900, 256, 0, stream>>>(off, crdb, w4b);
    k_gather   <<<800, 256, 0, stream>>>(xT, crdb, w4b, Ahi);
    k_dmfma    <<<800, 512, 0, stream>>>(Ahi, wB1, bias, out);
    k_bnstats  <<<256, 256, 0, stream>>>(out, stats);
    k_bnsilu   <<<2048, 256, 0, stream>>>(out, stats, gamma, beta);
}

// Round 25
// 217.267 us; speedup vs baseline: 1.2817x; 1.2817x over previous
//
#include <hip/hip_runtime.h>
#include <math.h>

constexpr int Hc = 80, Wc = 80, Bn = 4, C1 = 256, C2 = 256;
constexpr int HWn = Hc * Wc;          // 6400
constexpr int NPIX = Bn * HWn;        // 25600
constexpr int OFFC = 27;
constexpr int KK   = 2304;            // C1*9

typedef short bf16x8 __attribute__((ext_vector_type(8)));
typedef float f32x4  __attribute__((ext_vector_type(4)));

__device__ __forceinline__ unsigned f2bf(float f) {   // RNE to bf16 bits
    unsigned u = __float_as_uint(f);
    return (u + 0x7FFF + ((u >> 16) & 1)) >> 16;
}

// pack 2 floats -> 1 u32 of 2 bf16 via cvt_pk (RNE)
__device__ __forceinline__ unsigned packhi2(float v0, float v1) {
    unsigned h;
    asm("v_cvt_pk_bf16_f32 %0, %1, %2" : "=v"(h) : "v"(v0), "v"(v1));
    return h;
}

// ---------------- kernel 0a: weight prep -> per-step B images, K-MAJOR ----------
__global__ __launch_bounds__(256) void k_wprep(const float* __restrict__ weight,
                                               unsigned short* __restrict__ wB1)
{
    int e = blockIdx.x * 256 + threadIdx.x;   // 0 .. 589823
    int kin = e & 7;
    int oc  = (e >> 3) & 255;
    int kg  = (e >> 11) & 3;
    int s   = e >> 13;                        // 0..71
    int p   = s >> 3, cc = s & 7;
    float w = weight[((size_t)oc * C1 + cc * 32 + kg * 8 + kin) * 9 + p];
    wB1[e] = (unsigned short)f2bf(w);
}

// ---------------- kernel 0b: offset-conv MFMA weight prep -> wOB[s][32][32] ----
__global__ __launch_bounds__(256) void k_wobprep(const float* __restrict__ w_off,
                                                 unsigned short* __restrict__ wOB)
{
    int e = blockIdx.x * 256 + threadIdx.x;   // 0 .. 73727
    int k  = e & 31;
    int oc = (e >> 5) & 31;
    int s  = e >> 10;                         // 0..71
    int p  = s >> 3, cc = s & 7;
    float v = 0.f;
    if (oc < 27) v = w_off[((size_t)oc * C1 + cc * 32 + k) * 9 + p];
    wOB[e] = (unsigned short)f2bf(v);
}

// ---------------- kernel 0c: x transpose -> xT[b][hw][c] (f32) + xTb (bf16) ----
__global__ __launch_bounds__(256) void k_xtrans(const float* __restrict__ x,
                                                float* __restrict__ xT,
                                                unsigned short* __restrict__ xTb)
{
    __shared__ float tile[32][33];
    int bid = blockIdx.x;                 // b*(200*8) + hwt*8 + ct
    int ct  = bid & 7;
    int hwt = (bid >> 3) % 200;
    int b   = bid / 1600;
    int c0  = ct * 32, hw0 = hwt * 32;
    int tid = threadIdx.x;
    int col = tid & 31, rw = tid >> 5;    // 8 rows per pass
    const float* xb = x + (size_t)b * C1 * HWn;
    #pragma unroll
    for (int k = 0; k < 4; ++k) {
        int r = rw + k * 8;               // c-index
        tile[r][col] = xb[(size_t)(c0 + r) * HWn + hw0 + col];
    }
    __syncthreads();
    float* xo = xT + ((size_t)b * HWn + hw0) * C1 + c0;
    unsigned short* xob = xTb + ((size_t)b * HWn + hw0) * C1 + c0;
    #pragma unroll
    for (int k = 0; k < 4; ++k) {
        int r = rw + k * 8;               // hw-index
        float v = tile[col][r];
        xo[(size_t)r * C1 + col]  = v;
        xob[(size_t)r * C1 + col] = (unsigned short)f2bf(v);
    }
}

// ---------------- kernel 1b: offset conv v4 — MFMA, no LDS, no barriers --------
__global__ __launch_bounds__(256) void k_offmfma(const unsigned short* __restrict__ xTb,
                                                 const unsigned short* __restrict__ wOB,
                                                 const float* __restrict__ b_off,
                                                 float* __restrict__ off)
{
    int t  = threadIdx.x;
    int wv = t >> 6, lane = t & 63;
    int li = lane & 15, kg = lane >> 4;
    int mi = wv & 1;                   // m-tile (16 px)
    int nj = wv >> 1;                  // n-tile (16 oc)

    int mtile = ((blockIdx.x & 7) * 100) + (blockIdx.x >> 3);
    int m0  = mtile * 32;
    int b   = m0 / HWn;                // uniform per block
    int hw0 = m0 - b * HWn;
    int pxl = hw0 + mi * 16 + li;      // this lane's hw (A row)
    int h = pxl / Wc, w = pxl - h * Wc;

    const unsigned short* xb = xTb + (size_t)b * HWn * C1;

    f32x4 acc = (f32x4){0.f, 0.f, 0.f, 0.f};
    #pragma unroll
    for (int p = 0; p < 9; ++p) {
        int dh = p / 3 - 1, dw = p % 3 - 1;
        int hh = h + dh, ww = w + dw;
        bool valid = (hh >= 0 && hh < Hc && ww >= 0 && ww < Wc);
        int hwp = valid ? (hh * Wc + ww) : 0;
        const unsigned short* arow = xb + (size_t)hwp * C1 + kg * 8;
        const unsigned short* brow = wOB + ((size_t)(p * 8) * 32 + nj * 16 + li) * 32 + kg * 8;
        #pragma unroll
        for (int cc = 0; cc < 8; ++cc) {
            uint4 av = *(const uint4*)(arow + cc * 32);
            if (!valid) av = make_uint4(0, 0, 0, 0);
            uint4 bv = *(const uint4*)(brow + cc * 1024);   // next s: +32*32 u16
            acc = __builtin_amdgcn_mfma_f32_16x16x32_bf16(
                __builtin_bit_cast(bf16x8, av), __builtin_bit_cast(bf16x8, bv), acc, 0, 0, 0);
        }
    }
    int oc = nj * 16 + li;
    if (oc < OFFC) {
        float bs = b_off[oc];
        float4 v;
        v.x = acc[0] + bs; v.y = acc[1] + bs; v.z = acc[2] + bs; v.w = acc[3] + bs;
        int hwd = hw0 + mi * 16 + kg * 4;
        *(float4*)&off[((size_t)b * OFFC + oc) * HWn + hwd] = v;
    }
}

// ---------------- kernel 1c-pre: bilinear metadata table ----------------
__global__ __launch_bounds__(256) void k_meta(const float* __restrict__ off,
                                              int* __restrict__ crdbuf,
                                              float4* __restrict__ w4buf)
{
    int pair = blockIdx.x * 256 + threadIdx.x;   // 0 .. 230399
    int px = pair / 9, p = pair - px * 9;
    int b  = px / HWn, hw = px - b * HWn;
    int h = hw / Wc, w = hw - h * Wc;
    int ii = p / 3, jj = p - ii * 3;

    const float* ob = off + (size_t)b * OFFC * HWn + hw;
    float dy = ob[(2 * p) * HWn];
    float dx = ob[(2 * p + 1) * HWn];
    float mv = ob[(18 + p) * HWn];
    float mask = 1.0f / (1.0f + expf(-mv));
    float ys = dy + (float)(h - 1 + ii);
    float xsv = dx + (float)(w - 1 + jj);
    float y0f = floorf(ys), x0f = floorf(xsv);
    float wy = ys - y0f, wx = xsv - x0f;
    int y0 = (int)y0f, x0 = (int)x0f;
    int y1 = y0 + 1, x1 = x0 + 1;
    float vy0 = (y0 >= 0 && y0 < Hc) ? 1.f : 0.f;
    float vy1 = (y1 >= 0 && y1 < Hc) ? 1.f : 0.f;
    float vx0 = (x0 >= 0 && x0 < Wc) ? 1.f : 0.f;
    float vx1 = (x1 >= 0 && x1 < Wc) ? 1.f : 0.f;
    float4 wv;
    wv.x = mask * (1.f - wy) * (1.f - wx) * vy0 * vx0;
    wv.y = mask * (1.f - wy) * wx         * vy0 * vx1;
    wv.z = mask * wy         * (1.f - wx) * vy1 * vx0;
    wv.w = mask * wy         * wx         * vy1 * vx1;
    int cy0 = min(max(y0, 0), Hc - 1), cy1 = min(max(y1, 0), Hc - 1);
    int cx0 = min(max(x0, 0), Wc - 1), cx1 = min(max(x1, 0), Wc - 1);
    crdbuf[pair] = cy0 | (cy1 << 8) | (cx0 << 16) | (cx1 << 24);
    w4buf[pair]  = wv;
}

// ---------------- kernel 1c: materialize patches v6 — 3200 blocks TLP ----------
// round-24: gather is latency-bound with independent iterations; grid 800->
// 3200 (18 pairs/wave) quadruples wave count at identical traffic.
// XCD chunking preserved: 3200 = 8 x 400; XCD k owns pairs [k*28800, ...).
__global__ __launch_bounds__(256) void k_gather(const float* __restrict__ xT,
                                                const int* __restrict__ crdbuf,
                                                const float4* __restrict__ w4buf,
                                                unsigned short* __restrict__ Ahi)
{
    int t   = threadIdx.x;
    int wv  = t >> 6, l = t & 63;
    int xcd = blockIdx.x & 7;
    int blk = blockIdx.x >> 3;               // 0..399 within XCD
    int wgl = (xcd * 400 + blk) * 4 + wv;    // global wave 0..12799
    int base = wgl * 18;

    #pragma unroll 2
    for (int i = 0; i < 18; ++i) {
        int pair = base + i;
        int px = pair / 9, p = pair - px * 9;
        int b  = px / HWn;
        int crd = crdbuf[pair];
        float4 w4 = w4buf[pair];
        int cy0 = crd & 255, cy1 = (crd >> 8) & 255;
        int cx0 = (crd >> 16) & 255, cx1 = (crd >> 24) & 255;
        const float* xt = xT + (size_t)b * HWn * C1;
        const float4* g00p = (const float4*)&xt[(size_t)(cy0 * Wc + cx0) * C1];
        const float4* g01p = (const float4*)&xt[(size_t)(cy0 * Wc + cx1) * C1];
        const float4* g10p = (const float4*)&xt[(size_t)(cy1 * Wc + cx0) * C1];
        const float4* g11p = (const float4*)&xt[(size_t)(cy1 * Wc + cx1) * C1];
        float4 g00 = g00p[l], g01 = g01p[l], g10 = g10p[l], g11 = g11p[l];
        float vx = fmaf(w4.x, g00.x, fmaf(w4.y, g01.x, fmaf(w4.z, g10.x, w4.w * g11.x)));
        float vy = fmaf(w4.x, g00.y, fmaf(w4.y, g01.y, fmaf(w4.z, g10.y, w4.w * g11.y)));
        float vz = fmaf(w4.x, g00.z, fmaf(w4.y, g01.z, fmaf(w4.z, g10.z, w4.w * g11.z)));
        float vw = fmaf(w4.x, g00.w, fmaf(w4.y, g01.w, fmaf(w4.z, g10.w, w4.w * g11.w)));
        unsigned h0 = packhi2(vx, vy), h1 = packhi2(vz, vw);
        int s = p * 8 + (l >> 3);
        size_t aidx = ((size_t)s * NPIX + px) * 32 + 4 * (l & 7);
        *(uint2*)&Ahi[aidx] = make_uint2(h0, h1);
    }
}

// ------------- kernel 2: dense streaming MFMA GEMM v10 (r20, 77.4us) -------------
// r24 verdict: dur tracks traffic (dur/FETCH const across r23/r24); 8-wave
// split doubled A-dup traffic and slowed down. v10 restored verbatim.
__global__ __launch_bounds__(256) void k_dmfma(const unsigned short* __restrict__ Ahi,
                                               const unsigned short* __restrict__ wB1,
                                               const float* __restrict__ bias,
                                               float* __restrict__ out)
{
    __shared__ float Tb[32 * 33];      // epilogue transpose only (4224 B)

    int t  = threadIdx.x;
    int wv = t >> 6, lane = t & 63;
    int li = lane & 15, kg = lane >> 4;
    int nh = wv;                       // oc 64-slot (4 waves x 64 oc)

    int mtile = ((blockIdx.x & 7) * 100) + (blockIdx.x >> 3);
    int m0  = mtile * 32;
    int b   = m0 / HWn;
    int hw0 = m0 - b * HWn;
    int row0 = m0 + li;                // m-frag 0 row
    int row1 = m0 + 16 + li;           // m-frag 1 row

    const unsigned short* a0p = Ahi + (size_t)row0 * 32 + kg * 8;
    const unsigned short* a1p = Ahi + (size_t)row1 * 32 + kg * 8;
    const unsigned short* bp  = wB1 + (size_t)(kg * 256 + nh * 64 + li) * 8;

    auto loadA = [&](int s, uint4& h0, uint4& h1) {
        size_t o = (size_t)s * NPIX * 32;
        h0 = *(const uint4*)(a0p + o);
        h1 = *(const uint4*)(a1p + o);
    };
    auto loadB = [&](int s, uint4& b0, uint4& b1, uint4& b2, uint4& b3) {
        const unsigned short* q = bp + (size_t)s * 8192;
        b0 = *(const uint4*)(q);
        b1 = *(const uint4*)(q + 128);     // nt*16*8 u16
        b2 = *(const uint4*)(q + 256);
        b3 = *(const uint4*)(q + 384);
    };

    f32x4 acc[2][4];
    #pragma unroll
    for (int m = 0; m < 2; ++m)
        #pragma unroll
        for (int n = 0; n < 4; ++n) acc[m][n] = (f32x4){0.f, 0.f, 0.f, 0.f};

    uint4 aA0, aA1, bA0, bA1, bA2, bA3;    // stage A
    uint4 aB0, aB1, bB0, bB1, bB2, bB3;    // stage B

    auto compute = [&](uint4& c0, uint4& c1, uint4& q0, uint4& q1, uint4& q2, uint4& q3) {
        bf16x8 a0 = __builtin_bit_cast(bf16x8, c0);
        bf16x8 a1 = __builtin_bit_cast(bf16x8, c1);
        __builtin_amdgcn_s_setprio(1);
        bf16x8 v;
        v = __builtin_bit_cast(bf16x8, q0);
        acc[0][0] = __builtin_amdgcn_mfma_f32_16x16x32_bf16(a0, v, acc[0][0], 0, 0, 0);
        acc[1][0] = __builtin_amdgcn_mfma_f32_16x16x32_bf16(a1, v, acc[1][0], 0, 0, 0);
        v = __builtin_bit_cast(bf16x8, q1);
        acc[0][1] = __builtin_amdgcn_mfma_f32_16x16x32_bf16(a0, v, acc[0][1], 0, 0, 0);
        acc[1][1] = __builtin_amdgcn_mfma_f32_16x16x32_bf16(a1, v, acc[1][1], 0, 0, 0);
        v = __builtin_bit_cast(bf16x8, q2);
        acc[0][2] = __builtin_amdgcn_mfma_f32_16x16x32_bf16(a0, v, acc[0][2], 0, 0, 0);
        acc[1][2] = __builtin_amdgcn_mfma_f32_16x16x32_bf16(a1, v, acc[1][2], 0, 0, 0);
        v = __builtin_bit_cast(bf16x8, q3);
        acc[0][3] = __builtin_amdgcn_mfma_f32_16x16x32_bf16(a0, v, acc[0][3], 0, 0, 0);
        acc[1][3] = __builtin_amdgcn_mfma_f32_16x16x32_bf16(a1, v, acc[1][3], 0, 0, 0);
        __builtin_amdgcn_s_setprio(0);
    };

    loadA(0, aA0, aA1); loadB(0, bA0, bA1, bA2, bA3);
    for (int s = 0; s < 72; s += 2) {
        loadA(s + 1, aB0, aB1); loadB(s + 1, bB0, bB1, bB2, bB3);
        compute(aA0, aA1, bA0, bA1, bA2, bA3);
        if (s + 2 < 72) { loadA(s + 2, aA0, aA1); loadB(s + 2, bA0, bA1, bA2, bA3); }
        compute(aB0, aB1, bB0, bB1, bB2, bB3);
    }

    // ---- epilogue: 8 phases of 32 oc through Tb[32][33] ----
    #pragma unroll
    for (int q = 0; q < 8; ++q) {
        __syncthreads();
        if (nh == (q >> 1)) {
            #pragma unroll
            for (int jj = 0; jj < 2; ++jj) {
                int nt = (q & 1) * 2 + jj;
                #pragma unroll
                for (int m = 0; m < 2; ++m) {
                    f32x4 a = acc[m][nt];
                    int rrw = jj * 16 + li;             // oc row 0..31
                    int col = m * 16 + kg * 4;          // pixel col
                    #pragma unroll
                    for (int r = 0; r < 4; ++r)
                        Tb[rrw * 33 + col + r] = a[r];
                }
            }
        }
        __syncthreads();
        int px = t & 31;
        int rw = t >> 5;                    // 0..7
        #pragma unroll
        for (int it = 0; it < 4; ++it) {
            int r  = it * 8 + rw;           // 0..31
            int oc = q * 32 + r;
            out[(size_t)(b * C2 + oc) * HWn + hw0 + px] = Tb[r * 33 + px] + bias[oc];
        }
    }
}

// ---------------- kernel 3a: BN partial sums (1024 blocks, float4) ----------------
// round-24: old bnstats was 1 block/oc scalar (latency-bound ~12us). Now
// block = (oc, batch): 1600 float4 each, LDS reduce, atomic f32 partials.
__global__ __launch_bounds__(256) void k_bnpart(const float* __restrict__ out,
                                                float* __restrict__ psum)
{
    int oc = blockIdx.x >> 2;
    int bq = blockIdx.x & 3;
    const float4* src = (const float4*)(out + ((size_t)(bq * C2 + oc)) * HWn);
    float s = 0.f, ss = 0.f;
    for (int i = threadIdx.x; i < 1600; i += 256) {
        float4 v = src[i];
        s  += v.x + v.y + v.z + v.w;
        ss += v.x * v.x + v.y * v.y + v.z * v.z + v.w * v.w;
    }
    __shared__ float ls[256], lss[256];
    ls[threadIdx.x] = s; lss[threadIdx.x] = ss;
    __syncthreads();
    for (int st = 128; st > 0; st >>= 1) {
        if (threadIdx.x < st) {
            ls[threadIdx.x]  += ls[threadIdx.x + st];
            lss[threadIdx.x] += lss[threadIdx.x + st];
        }
        __syncthreads();
    }
    if (threadIdx.x == 0) {
        atomicAdd(&psum[oc], ls[0]);
        atomicAdd(&psum[256 + oc], lss[0]);
    }
}

// ---------------- kernel 3b: BN finalize ----------------
__global__ __launch_bounds__(256) void k_bnfin(const float* __restrict__ psum,
                                               float* __restrict__ stats)
{
    int oc = threadIdx.x;
    float mean = psum[oc] / (float)NPIX;
    float var  = psum[256 + oc] / (float)NPIX - mean * mean;
    stats[oc]       = mean;
    stats[256 + oc] = rsqrtf(var + 1e-5f);
}

// ---------------- kernel 4: BN normalize + affine + SiLU (in-place) ----------------
__global__ __launch_bounds__(256) void k_bnsilu(float* __restrict__ out,
                                                const float* __restrict__ stats,
                                                const float* __restrict__ gamma,
                                                const float* __restrict__ beta)
{
    int n4 = (Bn * C2 * HWn) / 4;
    for (int i = blockIdx.x * blockDim.x + threadIdx.x; i < n4;
         i += gridDim.x * blockDim.x) {
        float4 v = ((float4*)out)[i];
        int e  = i * 4;
        int oc = (e / HWn) & 255;
        float mean = stats[oc];
        float gs   = gamma[oc] * stats[256 + oc];
        float bt   = beta[oc];
        float y;
        y = (v.x - mean) * gs + bt; v.x = y / (1.f + expf(-y));
        y = (v.y - mean) * gs + bt; v.y = y / (1.f + expf(-y));
        y = (v.z - mean) * gs + bt; v.z = y / (1.f + expf(-y));
        y = (v.w - mean) * gs + bt; v.w = y / (1.f + expf(-y));
        ((float4*)out)[i] = v;
    }
}

extern "C" void kernel_launch(void* const* d_in, const int* in_sizes, int n_in,
                              void* d_out, int out_size, void* d_ws, size_t ws_size,
                              hipStream_t stream)
{
    const float* x      = (const float*)d_in[0];
    const float* w_off  = (const float*)d_in[1];
    const float* b_off  = (const float*)d_in[2];
    const float* weight = (const float*)d_in[3];
    const float* bias   = (const float*)d_in[4];
    const float* gamma  = (const float*)d_in[5];
    const float* beta   = (const float*)d_in[6];
    float* out = (float*)d_out;

    // workspace layout (~158 MiB total)
    char* wsb = (char*)d_ws;
    unsigned short* Ahi  = (unsigned short*)(wsb);                 // 117,964,800 B
    float*          xT   = (float*)(wsb + 117964800);              //  26,214,400 B
    unsigned short* xTb  = (unsigned short*)(wsb + 144179200);     //  13,107,200 B
    float*          off  = (float*)(wsb + 157286400);              //   2,764,800 B
    unsigned short* wB1  = (unsigned short*)(wsb + 160051200);     //   1,179,648 B
    unsigned short* wOB  = (unsigned short*)(wsb + 161230848);     //     147,456 B
    int*            crdb = (int*)(wsb + 161378304);                //     921,600 B
    float4*         w4b  = (float4*)(wsb + 162299904);             //   3,686,400 B
    float*         stats = (float*)(wsb + 165986304);              //       2,048 B
    float*         psum  = (float*)(wsb + 165988352);              //       2,048 B

    hipMemsetAsync(psum, 0, 2048, stream);
    k_wprep    <<<2304, 256, 0, stream>>>(weight, wB1);
    k_wobprep  <<<288, 256, 0, stream>>>(w_off, wOB);
    k_xtrans   <<<6400, 256, 0, stream>>>(x, xT, xTb);
    k_offmfma  <<<800, 256, 0, stream>>>(xTb, wOB, b_off, off);
    k_meta     <<<900, 256, 0, stream>>>(off, crdb, w4b);
    k_gather   <<<3200, 256, 0, stream>>>(xT, crdb, w4b, Ahi);
    k_dmfma    <<<800, 256, 0, stream>>>(Ahi, wB1, bias, out);
    k_bnpart   <<<1024, 256, 0, stream>>>(out, psum);
    k_bnfin    <<<1, 256, 0, stream>>>(psum, stats);
    k_bnsilu   <<<2048, 256, 0, stream>>>(out, stats, gamma, beta);
}

// Round 26
// 211.683 us; speedup vs baseline: 1.3155x; 1.0264x over previous
//
#include <hip/hip_runtime.h>
#include <math.h>

constexpr int Hc = 80, Wc = 80, Bn = 4, C1 = 256, C2 = 256;
constexpr int HWn = Hc * Wc;          // 6400
constexpr int NPIX = Bn * HWn;        // 25600
constexpr int OFFC = 27;
constexpr int KK   = 2304;            // C1*9

typedef short bf16x8 __attribute__((ext_vector_type(8)));
typedef float f32x4  __attribute__((ext_vector_type(4)));

__device__ __forceinline__ unsigned f2bf(float f) {   // RNE to bf16 bits
    unsigned u = __float_as_uint(f);
    return (u + 0x7FFF + ((u >> 16) & 1)) >> 16;
}

// pack 2 floats -> 1 u32 of 2 bf16 via cvt_pk (RNE)
__device__ __forceinline__ unsigned packhi2(float v0, float v1) {
    unsigned h;
    asm("v_cvt_pk_bf16_f32 %0, %1, %2" : "=v"(h) : "v"(v0), "v"(v1));
    return h;
}

// unpack 4 bf16 (uint2) -> 4 f32
__device__ __forceinline__ void ub4(uint2 u, float f[4]) {
    f[0] = __uint_as_float(u.x << 16);
    f[1] = __uint_as_float(u.x & 0xffff0000u);
    f[2] = __uint_as_float(u.y << 16);
    f[3] = __uint_as_float(u.y & 0xffff0000u);
}

// ---------------- kernel 0a: weight prep -> per-step B images, K-MAJOR ----------
__global__ __launch_bounds__(256) void k_wprep(const float* __restrict__ weight,
                                               unsigned short* __restrict__ wB1)
{
    int e = blockIdx.x * 256 + threadIdx.x;   // 0 .. 589823
    int kin = e & 7;
    int oc  = (e >> 3) & 255;
    int kg  = (e >> 11) & 3;
    int s   = e >> 13;                        // 0..71
    int p   = s >> 3, cc = s & 7;
    float w = weight[((size_t)oc * C1 + cc * 32 + kg * 8 + kin) * 9 + p];
    wB1[e] = (unsigned short)f2bf(w);
}

// ---------------- kernel 0b: offset-conv MFMA weight prep -> wOB[s][32][32] ----
__global__ __launch_bounds__(256) void k_wobprep(const float* __restrict__ w_off,
                                                 unsigned short* __restrict__ wOB)
{
    int e = blockIdx.x * 256 + threadIdx.x;   // 0 .. 73727
    int k  = e & 31;
    int oc = (e >> 5) & 31;
    int s  = e >> 10;                         // 0..71
    int p  = s >> 3, cc = s & 7;
    float v = 0.f;
    if (oc < 27) v = w_off[((size_t)oc * C1 + cc * 32 + k) * 9 + p];
    wOB[e] = (unsigned short)f2bf(v);
}

// ---------------- kernel 0c: x transpose -> xTb[b][hw][c] (bf16 only) ----------
// round-25: dropped the f32 xT plane (gather now reads bf16 corners;
// error adds ~0.002 in quadrature vs observed 0.031). Saves 26MB writes.
__global__ __launch_bounds__(256) void k_xtrans(const float* __restrict__ x,
                                                unsigned short* __restrict__ xTb)
{
    __shared__ float tile[32][33];
    int bid = blockIdx.x;                 // b*(200*8) + hwt*8 + ct
    int ct  = bid & 7;
    int hwt = (bid >> 3) % 200;
    int b   = bid / 1600;
    int c0  = ct * 32, hw0 = hwt * 32;
    int tid = threadIdx.x;
    int col = tid & 31, rw = tid >> 5;    // 8 rows per pass
    const float* xb = x + (size_t)b * C1 * HWn;
    #pragma unroll
    for (int k = 0; k < 4; ++k) {
        int r = rw + k * 8;               // c-index
        tile[r][col] = xb[(size_t)(c0 + r) * HWn + hw0 + col];
    }
    __syncthreads();
    unsigned short* xob = xTb + ((size_t)b * HWn + hw0) * C1 + c0;
    #pragma unroll
    for (int k = 0; k < 4; ++k) {
        int r = rw + k * 8;               // hw-index
        xob[(size_t)r * C1 + col] = (unsigned short)f2bf(tile[col][r]);
    }
}

// ---------------- kernel 1b: offset conv v4 — MFMA, no LDS, no barriers --------
__global__ __launch_bounds__(256) void k_offmfma(const unsigned short* __restrict__ xTb,
                                                 const unsigned short* __restrict__ wOB,
                                                 const float* __restrict__ b_off,
                                                 float* __restrict__ off)
{
    int t  = threadIdx.x;
    int wv = t >> 6, lane = t & 63;
    int li = lane & 15, kg = lane >> 4;
    int mi = wv & 1;                   // m-tile (16 px)
    int nj = wv >> 1;                  // n-tile (16 oc)

    int mtile = ((blockIdx.x & 7) * 100) + (blockIdx.x >> 3);
    int m0  = mtile * 32;
    int b   = m0 / HWn;                // uniform per block
    int hw0 = m0 - b * HWn;
    int pxl = hw0 + mi * 16 + li;      // this lane's hw (A row)
    int h = pxl / Wc, w = pxl - h * Wc;

    const unsigned short* xb = xTb + (size_t)b * HWn * C1;

    f32x4 acc = (f32x4){0.f, 0.f, 0.f, 0.f};
    #pragma unroll
    for (int p = 0; p < 9; ++p) {
        int dh = p / 3 - 1, dw = p % 3 - 1;
        int hh = h + dh, ww = w + dw;
        bool valid = (hh >= 0 && hh < Hc && ww >= 0 && ww < Wc);
        int hwp = valid ? (hh * Wc + ww) : 0;
        const unsigned short* arow = xb + (size_t)hwp * C1 + kg * 8;
        const unsigned short* brow = wOB + ((size_t)(p * 8) * 32 + nj * 16 + li) * 32 + kg * 8;
        #pragma unroll
        for (int cc = 0; cc < 8; ++cc) {
            uint4 av = *(const uint4*)(arow + cc * 32);
            if (!valid) av = make_uint4(0, 0, 0, 0);
            uint4 bv = *(const uint4*)(brow + cc * 1024);   // next s: +32*32 u16
            acc = __builtin_amdgcn_mfma_f32_16x16x32_bf16(
                __builtin_bit_cast(bf16x8, av), __builtin_bit_cast(bf16x8, bv), acc, 0, 0, 0);
        }
    }
    int oc = nj * 16 + li;
    if (oc < OFFC) {
        float bs = b_off[oc];
        float4 v;
        v.x = acc[0] + bs; v.y = acc[1] + bs; v.z = acc[2] + bs; v.w = acc[3] + bs;
        int hwd = hw0 + mi * 16 + kg * 4;
        *(float4*)&off[((size_t)b * OFFC + oc) * HWn + hwd] = v;
    }
}

// ---------------- kernel 1c-pre: bilinear metadata table ----------------
__global__ __launch_bounds__(256) void k_meta(const float* __restrict__ off,
                                              int* __restrict__ crdbuf,
                                              float4* __restrict__ w4buf)
{
    int pair = blockIdx.x * 256 + threadIdx.x;   // 0 .. 230399
    int px = pair / 9, p = pair - px * 9;
    int b  = px / HWn, hw = px - b * HWn;
    int h = hw / Wc, w = hw - h * Wc;
    int ii = p / 3, jj = p - ii * 3;

    const float* ob = off + (size_t)b * OFFC * HWn + hw;
    float dy = ob[(2 * p) * HWn];
    float dx = ob[(2 * p + 1) * HWn];
    float mv = ob[(18 + p) * HWn];
    float mask = 1.0f / (1.0f + expf(-mv));
    float ys = dy + (float)(h - 1 + ii);
    float xsv = dx + (float)(w - 1 + jj);
    float y0f = floorf(ys), x0f = floorf(xsv);
    float wy = ys - y0f, wx = xsv - x0f;
    int y0 = (int)y0f, x0 = (int)x0f;
    int y1 = y0 + 1, x1 = x0 + 1;
    float vy0 = (y0 >= 0 && y0 < Hc) ? 1.f : 0.f;
    float vy1 = (y1 >= 0 && y1 < Hc) ? 1.f : 0.f;
    float vx0 = (x0 >= 0 && x0 < Wc) ? 1.f : 0.f;
    float vx1 = (x1 >= 0 && x1 < Wc) ? 1.f : 0.f;
    float4 wv;
    wv.x = mask * (1.f - wy) * (1.f - wx) * vy0 * vx0;
    wv.y = mask * (1.f - wy) * wx         * vy0 * vx1;
    wv.z = mask * wy         * (1.f - wx) * vy1 * vx0;
    wv.w = mask * wy         * wx         * vy1 * vx1;
    int cy0 = min(max(y0, 0), Hc - 1), cy1 = min(max(y1, 0), Hc - 1);
    int cx0 = min(max(x0, 0), Wc - 1), cx1 = min(max(x1, 0), Wc - 1);
    crdbuf[pair] = cy0 | (cy1 << 8) | (cx0 << 16) | (cx1 << 24);
    w4buf[pair]  = wv;
}

// ---------------- kernel 1c: materialize patches v7 — bf16 corner reads --------
// 3200 blocks (18 pairs/wave, r25 TLP win kept). Corners read from xTb
// (uint2 = 4 bf16 ch), combined in f32, packed back to bf16.
__global__ __launch_bounds__(256) void k_gather(const unsigned short* __restrict__ xTb,
                                                const int* __restrict__ crdbuf,
                                                const float4* __restrict__ w4buf,
                                                unsigned short* __restrict__ Ahi)
{
    int t   = threadIdx.x;
    int wv  = t >> 6, l = t & 63;
    int xcd = blockIdx.x & 7;
    int blk = blockIdx.x >> 3;               // 0..399 within XCD
    int wgl = (xcd * 400 + blk) * 4 + wv;    // global wave 0..12799
    int base = wgl * 18;

    #pragma unroll 2
    for (int i = 0; i < 18; ++i) {
        int pair = base + i;
        int px = pair / 9, p = pair - px * 9;
        int b  = px / HWn;
        int crd = crdbuf[pair];
        float4 w4 = w4buf[pair];
        int cy0 = crd & 255, cy1 = (crd >> 8) & 255;
        int cx0 = (crd >> 16) & 255, cx1 = (crd >> 24) & 255;
        const unsigned short* xt = xTb + (size_t)b * HWn * C1;
        uint2 u00 = ((const uint2*)&xt[(size_t)(cy0 * Wc + cx0) * C1])[l];
        uint2 u01 = ((const uint2*)&xt[(size_t)(cy0 * Wc + cx1) * C1])[l];
        uint2 u10 = ((const uint2*)&xt[(size_t)(cy1 * Wc + cx0) * C1])[l];
        uint2 u11 = ((const uint2*)&xt[(size_t)(cy1 * Wc + cx1) * C1])[l];
        float f00[4], f01[4], f10[4], f11[4];
        ub4(u00, f00); ub4(u01, f01); ub4(u10, f10); ub4(u11, f11);
        float v0 = fmaf(w4.x, f00[0], fmaf(w4.y, f01[0], fmaf(w4.z, f10[0], w4.w * f11[0])));
        float v1 = fmaf(w4.x, f00[1], fmaf(w4.y, f01[1], fmaf(w4.z, f10[1], w4.w * f11[1])));
        float v2 = fmaf(w4.x, f00[2], fmaf(w4.y, f01[2], fmaf(w4.z, f10[2], w4.w * f11[2])));
        float v3 = fmaf(w4.x, f00[3], fmaf(w4.y, f01[3], fmaf(w4.z, f10[3], w4.w * f11[3])));
        unsigned h0 = packhi2(v0, v1), h1 = packhi2(v2, v3);
        int s = p * 8 + (l >> 3);
        size_t aidx = ((size_t)s * NPIX + px) * 32 + 4 * (l & 7);
        *(uint2*)&Ahi[aidx] = make_uint2(h0, h1);
    }
}

// ------------- kernel 2: dense streaming MFMA GEMM v14 — pinned pipeline -------------
// round-25 clue: VGPR=48 -> the allocator COLLAPSED every register pipeline
// (r20 v10, r23 4-deep) into load->wait->MFMA serial code; all "null" pipe
// results were artifacts. v14 = v10 + sched_barrier(0) fences around load
// issues + explicit vmcnt(6) between issue(s+1) and compute(s) (6 newer
// loads outstanding; stage-s regs drained; compiler dep-waits remain as
// backstop). Forces true double-buffer allocation.
__global__ __launch_bounds__(256) void k_dmfma(const unsigned short* __restrict__ Ahi,
                                               const unsigned short* __restrict__ wB1,
                                               const float* __restrict__ bias,
                                               float* __restrict__ out)
{
    __shared__ float Tb[32 * 33];      // epilogue transpose only (4224 B)

    int t  = threadIdx.x;
    int wv = t >> 6, lane = t & 63;
    int li = lane & 15, kg = lane >> 4;
    int nh = wv;                       // oc 64-slot (4 waves x 64 oc)

    int mtile = ((blockIdx.x & 7) * 100) + (blockIdx.x >> 3);
    int m0  = mtile * 32;
    int b   = m0 / HWn;
    int hw0 = m0 - b * HWn;
    int row0 = m0 + li;                // m-frag 0 row
    int row1 = m0 + 16 + li;           // m-frag 1 row

    const unsigned short* a0p = Ahi + (size_t)row0 * 32 + kg * 8;
    const unsigned short* a1p = Ahi + (size_t)row1 * 32 + kg * 8;
    const unsigned short* bp  = wB1 + (size_t)(kg * 256 + nh * 64 + li) * 8;

    auto loadA = [&](int s, uint4& h0, uint4& h1) {
        size_t o = (size_t)s * NPIX * 32;
        h0 = *(const uint4*)(a0p + o);
        h1 = *(const uint4*)(a1p + o);
    };
    auto loadB = [&](int s, uint4& b0, uint4& b1, uint4& b2, uint4& b3) {
        const unsigned short* q = bp + (size_t)s * 8192;
        b0 = *(const uint4*)(q);
        b1 = *(const uint4*)(q + 128);     // nt*16*8 u16
        b2 = *(const uint4*)(q + 256);
        b3 = *(const uint4*)(q + 384);
    };

    f32x4 acc[2][4];
    #pragma unroll
    for (int m = 0; m < 2; ++m)
        #pragma unroll
        for (int n = 0; n < 4; ++n) acc[m][n] = (f32x4){0.f, 0.f, 0.f, 0.f};

    uint4 aA0, aA1, bA0, bA1, bA2, bA3;    // stage A
    uint4 aB0, aB1, bB0, bB1, bB2, bB3;    // stage B

    auto compute = [&](uint4& c0, uint4& c1, uint4& q0, uint4& q1, uint4& q2, uint4& q3) {
        bf16x8 a0 = __builtin_bit_cast(bf16x8, c0);
        bf16x8 a1 = __builtin_bit_cast(bf16x8, c1);
        __builtin_amdgcn_s_setprio(1);
        bf16x8 v;
        v = __builtin_bit_cast(bf16x8, q0);
        acc[0][0] = __builtin_amdgcn_mfma_f32_16x16x32_bf16(a0, v, acc[0][0], 0, 0, 0);
        acc[1][0] = __builtin_amdgcn_mfma_f32_16x16x32_bf16(a1, v, acc[1][0], 0, 0, 0);
        v = __builtin_bit_cast(bf16x8, q1);
        acc[0][1] = __builtin_amdgcn_mfma_f32_16x16x32_bf16(a0, v, acc[0][1], 0, 0, 0);
        acc[1][1] = __builtin_amdgcn_mfma_f32_16x16x32_bf16(a1, v, acc[1][1], 0, 0, 0);
        v = __builtin_bit_cast(bf16x8, q2);
        acc[0][2] = __builtin_amdgcn_mfma_f32_16x16x32_bf16(a0, v, acc[0][2], 0, 0, 0);
        acc[1][2] = __builtin_amdgcn_mfma_f32_16x16x32_bf16(a1, v, acc[1][2], 0, 0, 0);
        v = __builtin_bit_cast(bf16x8, q3);
        acc[0][3] = __builtin_amdgcn_mfma_f32_16x16x32_bf16(a0, v, acc[0][3], 0, 0, 0);
        acc[1][3] = __builtin_amdgcn_mfma_f32_16x16x32_bf16(a1, v, acc[1][3], 0, 0, 0);
        __builtin_amdgcn_s_setprio(0);
    };

    loadA(0, aA0, aA1); loadB(0, bA0, bA1, bA2, bA3);
    for (int s = 0; s < 72; s += 2) {
        loadA(s + 1, aB0, aB1); loadB(s + 1, bB0, bB1, bB2, bB3);
        __builtin_amdgcn_sched_barrier(0);
        asm volatile("s_waitcnt vmcnt(6)" ::: "memory");
        __builtin_amdgcn_sched_barrier(0);
        compute(aA0, aA1, bA0, bA1, bA2, bA3);
        if (s + 2 < 72) { loadA(s + 2, aA0, aA1); loadB(s + 2, bA0, bA1, bA2, bA3); }
        __builtin_amdgcn_sched_barrier(0);
        if (s + 2 < 72) { asm volatile("s_waitcnt vmcnt(6)" ::: "memory"); }
        else            { asm volatile("s_waitcnt vmcnt(0)" ::: "memory"); }
        __builtin_amdgcn_sched_barrier(0);
        compute(aB0, aB1, bB0, bB1, bB2, bB3);
    }

    // ---- epilogue: 8 phases of 32 oc through Tb[32][33] ----
    #pragma unroll
    for (int q = 0; q < 8; ++q) {
        __syncthreads();
        if (nh == (q >> 1)) {
            #pragma unroll
            for (int jj = 0; jj < 2; ++jj) {
                int nt = (q & 1) * 2 + jj;
                #pragma unroll
                for (int m = 0; m < 2; ++m) {
                    f32x4 a = acc[m][nt];
                    int rrw = jj * 16 + li;             // oc row 0..31
                    int col = m * 16 + kg * 4;          // pixel col
                    #pragma unroll
                    for (int r = 0; r < 4; ++r)
                        Tb[rrw * 33 + col + r] = a[r];
                }
            }
        }
        __syncthreads();
        int px = t & 31;
        int rw = t >> 5;                    // 0..7
        #pragma unroll
        for (int it = 0; it < 4; ++it) {
            int r  = it * 8 + rw;           // 0..31
            int oc = q * 32 + r;
            out[(size_t)(b * C2 + oc) * HWn + hw0 + px] = Tb[r * 33 + px] + bias[oc];
        }
    }
}

// ---------------- kernel 3a: BN partial sums (1024 blocks, float4) ----------------
__global__ __launch_bounds__(256) void k_bnpart(const float* __restrict__ out,
                                                float* __restrict__ psum)
{
    int oc = blockIdx.x >> 2;
    int bq = blockIdx.x & 3;
    const float4* src = (const float4*)(out + ((size_t)(bq * C2 + oc)) * HWn);
    float s = 0.f, ss = 0.f;
    for (int i = threadIdx.x; i < 1600; i += 256) {
        float4 v = src[i];
        s  += v.x + v.y + v.z + v.w;
        ss += v.x * v.x + v.y * v.y + v.z * v.z + v.w * v.w;
    }
    __shared__ float ls[256], lss[256];
    ls[threadIdx.x] = s; lss[threadIdx.x] = ss;
    __syncthreads();
    for (int st = 128; st > 0; st >>= 1) {
        if (threadIdx.x < st) {
            ls[threadIdx.x]  += ls[threadIdx.x + st];
            lss[threadIdx.x] += lss[threadIdx.x + st];
        }
        __syncthreads();
    }
    if (threadIdx.x == 0) {
        atomicAdd(&psum[oc], ls[0]);
        atomicAdd(&psum[256 + oc], lss[0]);
    }
}

// ---------------- kernel 3b: BN finalize ----------------
__global__ __launch_bounds__(256) void k_bnfin(const float* __restrict__ psum,
                                               float* __restrict__ stats)
{
    int oc = threadIdx.x;
    float mean = psum[oc] / (float)NPIX;
    float var  = psum[256 + oc] / (float)NPIX - mean * mean;
    stats[oc]       = mean;
    stats[256 + oc] = rsqrtf(var + 1e-5f);
}

// ---------------- kernel 4: BN normalize + affine + SiLU (in-place) ----------------
__global__ __launch_bounds__(256) void k_bnsilu(float* __restrict__ out,
                                                const float* __restrict__ stats,
                                                const float* __restrict__ gamma,
                                                const float* __restrict__ beta)
{
    int n4 = (Bn * C2 * HWn) / 4;
    for (int i = blockIdx.x * blockDim.x + threadIdx.x; i < n4;
         i += gridDim.x * blockDim.x) {
        float4 v = ((float4*)out)[i];
        int e  = i * 4;
        int oc = (e / HWn) & 255;
        float mean = stats[oc];
        float gs   = gamma[oc] * stats[256 + oc];
        float bt   = beta[oc];
        float y;
        y = (v.x - mean) * gs + bt; v.x = y / (1.f + expf(-y));
        y = (v.y - mean) * gs + bt; v.y = y / (1.f + expf(-y));
        y = (v.z - mean) * gs + bt; v.z = y / (1.f + expf(-y));
        y = (v.w - mean) * gs + bt; v.w = y / (1.f + expf(-y));
        ((float4*)out)[i] = v;
    }
}

extern "C" void kernel_launch(void* const* d_in, const int* in_sizes, int n_in,
                              void* d_out, int out_size, void* d_ws, size_t ws_size,
                              hipStream_t stream)
{
    const float* x      = (const float*)d_in[0];
    const float* w_off  = (const float*)d_in[1];
    const float* b_off  = (const float*)d_in[2];
    const float* weight = (const float*)d_in[3];
    const float* bias   = (const float*)d_in[4];
    const float* gamma  = (const float*)d_in[5];
    const float* beta   = (const float*)d_in[6];
    float* out = (float*)d_out;

    // workspace layout (~134 MiB total; xT f32 dropped)
    char* wsb = (char*)d_ws;
    unsigned short* Ahi  = (unsigned short*)(wsb);                 // 117,964,800 B
    unsigned short* xTb  = (unsigned short*)(wsb + 117964800);     //  13,107,200 B
    float*          off  = (float*)(wsb + 131072000);              //   2,764,800 B
    unsigned short* wB1  = (unsigned short*)(wsb + 133836800);     //   1,179,648 B
    unsigned short* wOB  = (unsigned short*)(wsb + 135016448);     //     147,456 B
    int*            crdb = (int*)(wsb + 135163904);                //     921,600 B
    float4*         w4b  = (float4*)(wsb + 136085504);             //   3,686,400 B
    float*         stats = (float*)(wsb + 139771904);              //       2,048 B
    float*         psum  = (float*)(wsb + 139773952);              //       2,048 B

    hipMemsetAsync(psum, 0, 2048, stream);
    k_wprep    <<<2304, 256, 0, stream>>>(weight, wB1);
    k_wobprep  <<<288, 256, 0, stream>>>(w_off, wOB);
    k_xtrans   <<<6400, 256, 0, stream>>>(x, xTb);
    k_offmfma  <<<800, 256, 0, stream>>>(xTb, wOB, b_off, off);
    k_meta     <<<900, 256, 0, stream>>>(off, crdb, w4b);
    k_gather   <<<3200, 256, 0, stream>>>(xTb, crdb, w4b, Ahi);
    k_dmfma    <<<800, 256, 0, stream>>>(Ahi, wB1, bias, out);
    k_bnpart   <<<1024, 256, 0, stream>>>(out, psum);
    k_bnfin    <<<1, 256, 0, stream>>>(psum, stats);
    k_bnsilu   <<<2048, 256, 0, stream>>>(out, stats, gamma, beta);
}

// Round 27
// 202.145 us; speedup vs baseline: 1.3776x; 1.0472x over previous
//
#include <hip/hip_runtime.h>
#include <math.h>

constexpr int Hc = 80, Wc = 80, Bn = 4, C1 = 256, C2 = 256;
constexpr int HWn = Hc * Wc;          // 6400
constexpr int NPIX = Bn * HWn;        // 25600
constexpr int OFFC = 27;
constexpr int KK   = 2304;            // C1*9

typedef short bf16x8 __attribute__((ext_vector_type(8)));
typedef float f32x4  __attribute__((ext_vector_type(4)));

__device__ __forceinline__ unsigned f2bf(float f) {   // RNE to bf16 bits
    unsigned u = __float_as_uint(f);
    return (u + 0x7FFF + ((u >> 16) & 1)) >> 16;
}

// pack 2 floats -> 1 u32 of 2 bf16 via cvt_pk (RNE)
__device__ __forceinline__ unsigned packhi2(float v0, float v1) {
    unsigned h;
    asm("v_cvt_pk_bf16_f32 %0, %1, %2" : "=v"(h) : "v"(v0), "v"(v1));
    return h;
}

// unpack 4 bf16 (uint2) -> 4 f32
__device__ __forceinline__ void ub4(uint2 u, float f[4]) {
    f[0] = __uint_as_float(u.x << 16);
    f[1] = __uint_as_float(u.x & 0xffff0000u);
    f[2] = __uint_as_float(u.y << 16);
    f[3] = __uint_as_float(u.y & 0xffff0000u);
}

// ---------------- kernel 0: fused weight preps (wB1 + wOB) ----------------
// blocks 0..2303: wB1[s][kg][oc][8] k-major; blocks 2304..2591: wOB[s][32][32]
__global__ __launch_bounds__(256) void k_wprep2(const float* __restrict__ weight,
                                                const float* __restrict__ w_off,
                                                unsigned short* __restrict__ wB1,
                                                unsigned short* __restrict__ wOB)
{
    if (blockIdx.x < 2304) {
        int e = blockIdx.x * 256 + threadIdx.x;   // 0 .. 589823
        int kin = e & 7;
        int oc  = (e >> 3) & 255;
        int kg  = (e >> 11) & 3;
        int s   = e >> 13;                        // 0..71
        int p   = s >> 3, cc = s & 7;
        float w = weight[((size_t)oc * C1 + cc * 32 + kg * 8 + kin) * 9 + p];
        wB1[e] = (unsigned short)f2bf(w);
    } else {
        int e = (blockIdx.x - 2304) * 256 + threadIdx.x;   // 0 .. 73727
        int k  = e & 31;
        int oc = (e >> 5) & 31;
        int s  = e >> 10;                         // 0..71
        int p  = s >> 3, cc = s & 7;
        float v = 0.f;
        if (oc < 27) v = w_off[((size_t)oc * C1 + cc * 32 + k) * 9 + p];
        wOB[e] = (unsigned short)f2bf(v);
    }
}

// ---------------- kernel 0c: x transpose -> xTb[b][hw][c] (bf16 only) ----------
__global__ __launch_bounds__(256) void k_xtrans(const float* __restrict__ x,
                                                unsigned short* __restrict__ xTb)
{
    __shared__ float tile[32][33];
    int bid = blockIdx.x;                 // b*(200*8) + hwt*8 + ct
    int ct  = bid & 7;
    int hwt = (bid >> 3) % 200;
    int b   = bid / 1600;
    int c0  = ct * 32, hw0 = hwt * 32;
    int tid = threadIdx.x;
    int col = tid & 31, rw = tid >> 5;    // 8 rows per pass
    const float* xb = x + (size_t)b * C1 * HWn;
    #pragma unroll
    for (int k = 0; k < 4; ++k) {
        int r = rw + k * 8;               // c-index
        tile[r][col] = xb[(size_t)(c0 + r) * HWn + hw0 + col];
    }
    __syncthreads();
    unsigned short* xob = xTb + ((size_t)b * HWn + hw0) * C1 + c0;
    #pragma unroll
    for (int k = 0; k < 4; ++k) {
        int r = rw + k * 8;               // hw-index
        xob[(size_t)r * C1 + col] = (unsigned short)f2bf(tile[col][r]);
    }
}

// ---------------- kernel 1: offset conv MFMA + FUSED bilinear metadata ----------
// round-26: offmfma block holds all 27 off-channels for its 32 px ->
// stage [32][28] tile in LDS, compute the 288 (px,tap) meta entries
// in-block, write crd/w4 directly. Eliminates the off buffer (2.7MB
// write + read) and the k_meta launch.
__global__ __launch_bounds__(256) void k_offmeta(const unsigned short* __restrict__ xTb,
                                                 const unsigned short* __restrict__ wOB,
                                                 const float* __restrict__ b_off,
                                                 int* __restrict__ crdbuf,
                                                 float4* __restrict__ w4buf)
{
    __shared__ float offs[32][28];     // [px][ch] off tile (+pad)

    int t  = threadIdx.x;
    int wv = t >> 6, lane = t & 63;
    int li = lane & 15, kg = lane >> 4;
    int mi = wv & 1;                   // m-tile (16 px)
    int nj = wv >> 1;                  // n-tile (16 oc)

    int mtile = ((blockIdx.x & 7) * 100) + (blockIdx.x >> 3);
    int m0  = mtile * 32;
    int b   = m0 / HWn;                // uniform per block
    int hw0 = m0 - b * HWn;
    int pxl = hw0 + mi * 16 + li;      // this lane's hw (A row)
    int h = pxl / Wc, w = pxl - h * Wc;

    const unsigned short* xb = xTb + (size_t)b * HWn * C1;

    f32x4 acc = (f32x4){0.f, 0.f, 0.f, 0.f};
    #pragma unroll
    for (int p = 0; p < 9; ++p) {
        int dh = p / 3 - 1, dw = p % 3 - 1;
        int hh = h + dh, ww = w + dw;
        bool valid = (hh >= 0 && hh < Hc && ww >= 0 && ww < Wc);
        int hwp = valid ? (hh * Wc + ww) : 0;
        const unsigned short* arow = xb + (size_t)hwp * C1 + kg * 8;
        const unsigned short* brow = wOB + ((size_t)(p * 8) * 32 + nj * 16 + li) * 32 + kg * 8;
        #pragma unroll
        for (int cc = 0; cc < 8; ++cc) {
            uint4 av = *(const uint4*)(arow + cc * 32);
            if (!valid) av = make_uint4(0, 0, 0, 0);
            uint4 bv = *(const uint4*)(brow + cc * 1024);   // next s: +32*32 u16
            acc = __builtin_amdgcn_mfma_f32_16x16x32_bf16(
                __builtin_bit_cast(bf16x8, av), __builtin_bit_cast(bf16x8, bv), acc, 0, 0, 0);
        }
    }
    // stage off tile: D frag px = mi*16 + kg*4 + r, oc = nj*16 + li
    int oc = nj * 16 + li;
    if (oc < OFFC) {
        float bs = b_off[oc];
        #pragma unroll
        for (int r = 0; r < 4; ++r)
            offs[mi * 16 + kg * 4 + r][oc] = acc[r] + bs;
    }
    __syncthreads();

    // ---- fused metadata: 288 (px, tap) pairs ----
    for (int idx = t; idx < 288; idx += 256) {
        int pix = idx / 9, p = idx - pix * 9;
        int hw  = hw0 + pix;
        int hh = hw / Wc, wwp = hw - hh * Wc;
        int ii = p / 3, jj = p - ii * 3;
        float dy = offs[pix][2 * p];
        float dx = offs[pix][2 * p + 1];
        float mv = offs[pix][18 + p];
        float mask = 1.0f / (1.0f + expf(-mv));
        float ys  = dy + (float)(hh - 1 + ii);
        float xsv = dx + (float)(wwp - 1 + jj);
        float y0f = floorf(ys), x0f = floorf(xsv);
        float wy = ys - y0f, wx = xsv - x0f;
        int y0 = (int)y0f, x0 = (int)x0f;
        int y1 = y0 + 1, x1 = x0 + 1;
        float vy0 = (y0 >= 0 && y0 < Hc) ? 1.f : 0.f;
        float vy1 = (y1 >= 0 && y1 < Hc) ? 1.f : 0.f;
        float vx0 = (x0 >= 0 && x0 < Wc) ? 1.f : 0.f;
        float vx1 = (x1 >= 0 && x1 < Wc) ? 1.f : 0.f;
        float4 wv4;
        wv4.x = mask * (1.f - wy) * (1.f - wx) * vy0 * vx0;
        wv4.y = mask * (1.f - wy) * wx         * vy0 * vx1;
        wv4.z = mask * wy         * (1.f - wx) * vy1 * vx0;
        wv4.w = mask * wy         * wx         * vy1 * vx1;
        int cy0 = min(max(y0, 0), Hc - 1), cy1 = min(max(y1, 0), Hc - 1);
        int cx0 = min(max(x0, 0), Wc - 1), cx1 = min(max(x1, 0), Wc - 1);
        int pair = (m0 + pix) * 9 + p;
        crdbuf[pair] = cy0 | (cy1 << 8) | (cx0 << 16) | (cx1 << 24);
        w4buf[pair]  = wv4;
    }
}

// ---------------- kernel 1c: materialize patches v7 — bf16 corner reads --------
__global__ __launch_bounds__(256) void k_gather(const unsigned short* __restrict__ xTb,
                                                const int* __restrict__ crdbuf,
                                                const float4* __restrict__ w4buf,
                                                unsigned short* __restrict__ Ahi)
{
    int t   = threadIdx.x;
    int wv  = t >> 6, l = t & 63;
    int xcd = blockIdx.x & 7;
    int blk = blockIdx.x >> 3;               // 0..399 within XCD
    int wgl = (xcd * 400 + blk) * 4 + wv;    // global wave 0..12799
    int base = wgl * 18;

    #pragma unroll 2
    for (int i = 0; i < 18; ++i) {
        int pair = base + i;
        int px = pair / 9, p = pair - px * 9;
        int b  = px / HWn;
        int crd = crdbuf[pair];
        float4 w4 = w4buf[pair];
        int cy0 = crd & 255, cy1 = (crd >> 8) & 255;
        int cx0 = (crd >> 16) & 255, cx1 = (crd >> 24) & 255;
        const unsigned short* xt = xTb + (size_t)b * HWn * C1;
        uint2 u00 = ((const uint2*)&xt[(size_t)(cy0 * Wc + cx0) * C1])[l];
        uint2 u01 = ((const uint2*)&xt[(size_t)(cy0 * Wc + cx1) * C1])[l];
        uint2 u10 = ((const uint2*)&xt[(size_t)(cy1 * Wc + cx0) * C1])[l];
        uint2 u11 = ((const uint2*)&xt[(size_t)(cy1 * Wc + cx1) * C1])[l];
        float f00[4], f01[4], f10[4], f11[4];
        ub4(u00, f00); ub4(u01, f01); ub4(u10, f10); ub4(u11, f11);
        float v0 = fmaf(w4.x, f00[0], fmaf(w4.y, f01[0], fmaf(w4.z, f10[0], w4.w * f11[0])));
        float v1 = fmaf(w4.x, f00[1], fmaf(w4.y, f01[1], fmaf(w4.z, f10[1], w4.w * f11[1])));
        float v2 = fmaf(w4.x, f00[2], fmaf(w4.y, f01[2], fmaf(w4.z, f10[2], w4.w * f11[2])));
        float v3 = fmaf(w4.x, f00[3], fmaf(w4.y, f01[3], fmaf(w4.z, f10[3], w4.w * f11[3])));
        unsigned h0 = packhi2(v0, v1), h1 = packhi2(v2, v3);
        int s = p * 8 + (l >> 3);
        size_t aidx = ((size_t)s * NPIX + px) * 32 + 4 * (l & 7);
        *(uint2*)&Ahi[aidx] = make_uint2(h0, h1);
    }
}

// ------------- kernel 2: dense streaming MFMA GEMM (77.7us stable floor) -------------
__global__ __launch_bounds__(256) void k_dmfma(const unsigned short* __restrict__ Ahi,
                                               const unsigned short* __restrict__ wB1,
                                               const float* __restrict__ bias,
                                               float* __restrict__ out)
{
    __shared__ float Tb[32 * 33];      // epilogue transpose only (4224 B)

    int t  = threadIdx.x;
    int wv = t >> 6, lane = t & 63;
    int li = lane & 15, kg = lane >> 4;
    int nh = wv;                       // oc 64-slot (4 waves x 64 oc)

    int mtile = ((blockIdx.x & 7) * 100) + (blockIdx.x >> 3);
    int m0  = mtile * 32;
    int b   = m0 / HWn;
    int hw0 = m0 - b * HWn;
    int row0 = m0 + li;                // m-frag 0 row
    int row1 = m0 + 16 + li;           // m-frag 1 row

    const unsigned short* a0p = Ahi + (size_t)row0 * 32 + kg * 8;
    const unsigned short* a1p = Ahi + (size_t)row1 * 32 + kg * 8;
    const unsigned short* bp  = wB1 + (size_t)(kg * 256 + nh * 64 + li) * 8;

    auto loadA = [&](int s, uint4& h0, uint4& h1) {
        size_t o = (size_t)s * NPIX * 32;
        h0 = *(const uint4*)(a0p + o);
        h1 = *(const uint4*)(a1p + o);
    };
    auto loadB = [&](int s, uint4& b0, uint4& b1, uint4& b2, uint4& b3) {
        const unsigned short* q = bp + (size_t)s * 8192;
        b0 = *(const uint4*)(q);
        b1 = *(const uint4*)(q + 128);     // nt*16*8 u16
        b2 = *(const uint4*)(q + 256);
        b3 = *(const uint4*)(q + 384);
    };

    f32x4 acc[2][4];
    #pragma unroll
    for (int m = 0; m < 2; ++m)
        #pragma unroll
        for (int n = 0; n < 4; ++n) acc[m][n] = (f32x4){0.f, 0.f, 0.f, 0.f};

    uint4 aA0, aA1, bA0, bA1, bA2, bA3;    // stage A
    uint4 aB0, aB1, bB0, bB1, bB2, bB3;    // stage B

    auto compute = [&](uint4& c0, uint4& c1, uint4& q0, uint4& q1, uint4& q2, uint4& q3) {
        bf16x8 a0 = __builtin_bit_cast(bf16x8, c0);
        bf16x8 a1 = __builtin_bit_cast(bf16x8, c1);
        __builtin_amdgcn_s_setprio(1);
        bf16x8 v;
        v = __builtin_bit_cast(bf16x8, q0);
        acc[0][0] = __builtin_amdgcn_mfma_f32_16x16x32_bf16(a0, v, acc[0][0], 0, 0, 0);
        acc[1][0] = __builtin_amdgcn_mfma_f32_16x16x32_bf16(a1, v, acc[1][0], 0, 0, 0);
        v = __builtin_bit_cast(bf16x8, q1);
        acc[0][1] = __builtin_amdgcn_mfma_f32_16x16x32_bf16(a0, v, acc[0][1], 0, 0, 0);
        acc[1][1] = __builtin_amdgcn_mfma_f32_16x16x32_bf16(a1, v, acc[1][1], 0, 0, 0);
        v = __builtin_bit_cast(bf16x8, q2);
        acc[0][2] = __builtin_amdgcn_mfma_f32_16x16x32_bf16(a0, v, acc[0][2], 0, 0, 0);
        acc[1][2] = __builtin_amdgcn_mfma_f32_16x16x32_bf16(a1, v, acc[1][2], 0, 0, 0);
        v = __builtin_bit_cast(bf16x8, q3);
        acc[0][3] = __builtin_amdgcn_mfma_f32_16x16x32_bf16(a0, v, acc[0][3], 0, 0, 0);
        acc[1][3] = __builtin_amdgcn_mfma_f32_16x16x32_bf16(a1, v, acc[1][3], 0, 0, 0);
        __builtin_amdgcn_s_setprio(0);
    };

    loadA(0, aA0, aA1); loadB(0, bA0, bA1, bA2, bA3);
    for (int s = 0; s < 72; s += 2) {
        loadA(s + 1, aB0, aB1); loadB(s + 1, bB0, bB1, bB2, bB3);
        compute(aA0, aA1, bA0, bA1, bA2, bA3);
        if (s + 2 < 72) { loadA(s + 2, aA0, aA1); loadB(s + 2, bA0, bA1, bA2, bA3); }
        compute(aB0, aB1, bB0, bB1, bB2, bB3);
    }

    // ---- epilogue: 8 phases of 32 oc through Tb[32][33] ----
    #pragma unroll
    for (int q = 0; q < 8; ++q) {
        __syncthreads();
        if (nh == (q >> 1)) {
            #pragma unroll
            for (int jj = 0; jj < 2; ++jj) {
                int nt = (q & 1) * 2 + jj;
                #pragma unroll
                for (int m = 0; m < 2; ++m) {
                    f32x4 a = acc[m][nt];
                    int rrw = jj * 16 + li;             // oc row 0..31
                    int col = m * 16 + kg * 4;          // pixel col
                    #pragma unroll
                    for (int r = 0; r < 4; ++r)
                        Tb[rrw * 33 + col + r] = a[r];
                }
            }
        }
        __syncthreads();
        int px = t & 31;
        int rw = t >> 5;                    // 0..7
        #pragma unroll
        for (int it = 0; it < 4; ++it) {
            int r  = it * 8 + rw;           // 0..31
            int oc = q * 32 + r;
            out[(size_t)(b * C2 + oc) * HWn + hw0 + px] = Tb[r * 33 + px] + bias[oc];
        }
    }
}

// ---------------- kernel 3a: BN partials (no atomics, no memset) ----------------
// psum layout: [bq][oc] sums at 0..1023, sumsq at 1024..2047.
__global__ __launch_bounds__(256) void k_bnpart(const float* __restrict__ out,
                                                float* __restrict__ psum)
{
    int oc = blockIdx.x >> 2;
    int bq = blockIdx.x & 3;
    const float4* src = (const float4*)(out + ((size_t)(bq * C2 + oc)) * HWn);
    float s = 0.f, ss = 0.f;
    for (int i = threadIdx.x; i < 1600; i += 256) {
        float4 v = src[i];
        s  += v.x + v.y + v.z + v.w;
        ss += v.x * v.x + v.y * v.y + v.z * v.z + v.w * v.w;
    }
    __shared__ float ls[256], lss[256];
    ls[threadIdx.x] = s; lss[threadIdx.x] = ss;
    __syncthreads();
    for (int st = 128; st > 0; st >>= 1) {
        if (threadIdx.x < st) {
            ls[threadIdx.x]  += ls[threadIdx.x + st];
            lss[threadIdx.x] += lss[threadIdx.x + st];
        }
        __syncthreads();
    }
    if (threadIdx.x == 0) {
        psum[bq * 256 + oc]        = ls[0];
        psum[1024 + bq * 256 + oc] = lss[0];
    }
}

// ---------------- kernel 3b: BN finalize ----------------
__global__ __launch_bounds__(256) void k_bnfin(const float* __restrict__ psum,
                                               float* __restrict__ stats)
{
    int oc = threadIdx.x;
    float s  = psum[oc] + psum[256 + oc] + psum[512 + oc] + psum[768 + oc];
    float ss = psum[1024 + oc] + psum[1280 + oc] + psum[1536 + oc] + psum[1792 + oc];
    float mean = s / (float)NPIX;
    float var  = ss / (float)NPIX - mean * mean;
    stats[oc]       = mean;
    stats[256 + oc] = rsqrtf(var + 1e-5f);
}

// ---------------- kernel 4: BN normalize + affine + SiLU (in-place) ----------------
__global__ __launch_bounds__(256) void k_bnsilu(float* __restrict__ out,
                                                const float* __restrict__ stats,
                                                const float* __restrict__ gamma,
                                                const float* __restrict__ beta)
{
    int n4 = (Bn * C2 * HWn) / 4;
    for (int i = blockIdx.x * blockDim.x + threadIdx.x; i < n4;
         i += gridDim.x * blockDim.x) {
        float4 v = ((float4*)out)[i];
        int e  = i * 4;
        int oc = (e / HWn) & 255;
        float mean = stats[oc];
        float gs   = gamma[oc] * stats[256 + oc];
        float bt   = beta[oc];
        float y;
        y = (v.x - mean) * gs + bt; v.x = y / (1.f + expf(-y));
        y = (v.y - mean) * gs + bt; v.y = y / (1.f + expf(-y));
        y = (v.z - mean) * gs + bt; v.z = y / (1.f + expf(-y));
        y = (v.w - mean) * gs + bt; v.w = y / (1.f + expf(-y));
        ((float4*)out)[i] = v;
    }
}

extern "C" void kernel_launch(void* const* d_in, const int* in_sizes, int n_in,
                              void* d_out, int out_size, void* d_ws, size_t ws_size,
                              hipStream_t stream)
{
    const float* x      = (const float*)d_in[0];
    const float* w_off  = (const float*)d_in[1];
    const float* b_off  = (const float*)d_in[2];
    const float* weight = (const float*)d_in[3];
    const float* bias   = (const float*)d_in[4];
    const float* gamma  = (const float*)d_in[5];
    const float* beta   = (const float*)d_in[6];
    float* out = (float*)d_out;

    // workspace layout (~131 MiB total; off buffer dropped)
    char* wsb = (char*)d_ws;
    unsigned short* Ahi  = (unsigned short*)(wsb);                 // 117,964,800 B
    unsigned short* xTb  = (unsigned short*)(wsb + 117964800);     //  13,107,200 B
    unsigned short* wB1  = (unsigned short*)(wsb + 131072000);     //   1,179,648 B
    unsigned short* wOB  = (unsigned short*)(wsb + 132251648);     //     147,456 B
    int*            crdb = (int*)(wsb + 132399104);                //     921,600 B
    float4*         w4b  = (float4*)(wsb + 133320704);             //   3,686,400 B
    float*         stats = (float*)(wsb + 137007104);              //       2,048 B
    float*         psum  = (float*)(wsb + 137009152);              //       8,192 B

    k_wprep2  <<<2592, 256, 0, stream>>>(weight, w_off, wB1, wOB);
    k_xtrans  <<<6400, 256, 0, stream>>>(x, xTb);
    k_offmeta <<<800, 256, 0, stream>>>(xTb, wOB, b_off, crdb, w4b);
    k_gather  <<<3200, 256, 0, stream>>>(xTb, crdb, w4b, Ahi);
    k_dmfma   <<<800, 256, 0, stream>>>(Ahi, wB1, bias, out);
    k_bnpart  <<<1024, 256, 0, stream>>>(out, psum);
    k_bnfin   <<<1, 256, 0, stream>>>(psum, stats);
    k_bnsilu  <<<2048, 256, 0, stream>>>(out, stats, gamma, beta);
}